// Round 2
// baseline (156.861 us; speedup 1.0000x reference)
//
#include <hip/hip_runtime.h>

// KeySegPred — round 2: latency-optimized logits kernel.
// Kernel A (mlp_kernel): code = [emb_feat[src] | emb_dest[dest] | offset[:,1:3]]
//   h = relu(BN(code @ w1.T + b1)); out = h @ w2.T + b2  -> d_ws (4096x256 f32)
// Kernel B (logits_kernel):
//   phase 0: lanes 0..15 of each wave precompute tail[m] = emb_cand·out[252:256] + dense_b
//            (all scattered loads issued in parallel, once per wave)
//   phase 1: 4x-unrolled candidate loop, branch-free lane handling, interleaved butterflies

#define BATCH 4096
#define DSEG 128
#define DS_ 258
#define DM7 512
#define DM8 256
#define NCAND 64
#define DWC 252
#define TSLOTS 96
#define TROWS 8

__global__ __launch_bounds__(256) void mlp_kernel(
    const int* __restrict__ src, const int* __restrict__ dest,
    const float* __restrict__ offset,
    const float* __restrict__ emb_feat, const float* __restrict__ emb_dest,
    const float* __restrict__ w1, const float* __restrict__ b1,
    const float* __restrict__ bn_gamma, const float* __restrict__ bn_beta,
    const float* __restrict__ bn_mean, const float* __restrict__ bn_var,
    const float* __restrict__ w2, const float* __restrict__ b2,
    float* __restrict__ out_ws)
{
    __shared__ float code[TROWS][260];   // 258 used, row stride 1040B (16B aligned)
    __shared__ float hbuf[TROWS][516];   // 512 used, row stride 2064B (16B aligned)
    const int tid = threadIdx.x;
    const int b0 = blockIdx.x * TROWS;

    // ---- stage code tile: 8 rows x (128 + 128 + 2) ----
    {
        const int r = tid >> 5;   // 0..7
        const int i = tid & 31;   // 0..31
        const int bs = src[b0 + r];
        const int bd = dest[b0 + r];
        float4 v = *(const float4*)(emb_feat + (size_t)bs * DSEG + i * 4);
        *(float4*)&code[r][i * 4] = v;
        v = *(const float4*)(emb_dest + (size_t)bd * DSEG + i * 4);
        *(float4*)&code[r][128 + i * 4] = v;
        if (i == 0) {
            code[r][256] = offset[(b0 + r) * 4 + 1];
            code[r][257] = offset[(b0 + r) * 4 + 2];
        }
    }
    __syncthreads();

    // ---- MLP1: each thread owns cols c0=tid and c1=tid+256, 8 batch rows ----
    const int c0 = tid;
    const int c1 = tid + 256;
    float acc0[TROWS], acc1[TROWS];
#pragma unroll
    for (int r = 0; r < TROWS; ++r) { acc0[r] = 0.f; acc1[r] = 0.f; }
    // w1 rows are 258 floats = 1032B -> only 8B aligned, use float2
    const float2* __restrict__ w1a = (const float2*)(w1 + c0 * DS_);
    const float2* __restrict__ w1b = (const float2*)(w1 + c1 * DS_);
    for (int k4 = 0; k4 < 64; ++k4) {            // k = 0..255 via float4 LDS reads
        const float2 wa0 = w1a[2 * k4], wa1 = w1a[2 * k4 + 1];
        const float2 wb0 = w1b[2 * k4], wb1 = w1b[2 * k4 + 1];
#pragma unroll
        for (int r = 0; r < TROWS; ++r) {
            const float4 cv = *(const float4*)&code[r][k4 * 4];  // LDS broadcast b128
            acc0[r] = fmaf(wa0.x, cv.x, acc0[r]);
            acc0[r] = fmaf(wa0.y, cv.y, acc0[r]);
            acc0[r] = fmaf(wa1.x, cv.z, acc0[r]);
            acc0[r] = fmaf(wa1.y, cv.w, acc0[r]);
            acc1[r] = fmaf(wb0.x, cv.x, acc1[r]);
            acc1[r] = fmaf(wb0.y, cv.y, acc1[r]);
            acc1[r] = fmaf(wb1.x, cv.z, acc1[r]);
            acc1[r] = fmaf(wb1.y, cv.w, acc1[r]);
        }
    }
    {   // tail k = 256, 257
        const float2 wa = w1a[128];
        const float2 wb = w1b[128];
#pragma unroll
        for (int r = 0; r < TROWS; ++r) {
            const float2 cv = *(const float2*)&code[r][256];
            acc0[r] = fmaf(wa.x, cv.x, acc0[r]);
            acc0[r] = fmaf(wa.y, cv.y, acc0[r]);
            acc1[r] = fmaf(wb.x, cv.x, acc1[r]);
            acc1[r] = fmaf(wb.y, cv.y, acc1[r]);
        }
    }
    // ---- BN + ReLU -> hbuf ----
    {
        const float s0 = bn_gamma[c0] / sqrtf(bn_var[c0] + 1e-6f);
        const float s1 = bn_gamma[c1] / sqrtf(bn_var[c1] + 1e-6f);
        const float m0 = bn_mean[c0], m1 = bn_mean[c1];
        const float be0 = bn_beta[c0], be1 = bn_beta[c1];
        const float bb0 = b1[c0], bb1 = b1[c1];
#pragma unroll
        for (int r = 0; r < TROWS; ++r) {
            const float h0 = (acc0[r] + bb0 - m0) * s0 + be0;
            const float h1 = (acc1[r] + bb1 - m1) * s1 + be1;
            hbuf[r][c0] = fmaxf(h0, 0.f);
            hbuf[r][c1] = fmaxf(h1, 0.f);
        }
    }
    __syncthreads();

    // ---- MLP2: each thread owns out-col c0 (0..255), 8 batch rows ----
    float acc2[TROWS];
#pragma unroll
    for (int r = 0; r < TROWS; ++r) acc2[r] = 0.f;
    const float4* __restrict__ w2v = (const float4*)(w2 + c0 * DM7);  // 2048B rows, 16B aligned
    for (int k4 = 0; k4 < DM7 / 4; ++k4) {
        const float4 wv = w2v[k4];
#pragma unroll
        for (int r = 0; r < TROWS; ++r) {
            const float4 hv = *(const float4*)&hbuf[r][k4 * 4];  // LDS broadcast
            acc2[r] = fmaf(wv.x, hv.x, acc2[r]);
            acc2[r] = fmaf(wv.y, hv.y, acc2[r]);
            acc2[r] = fmaf(wv.z, hv.z, acc2[r]);
            acc2[r] = fmaf(wv.w, hv.w, acc2[r]);
        }
    }
    const float bo = b2[c0];
#pragma unroll
    for (int r = 0; r < TROWS; ++r) {
        out_ws[(size_t)(b0 + r) * DM8 + c0] = acc2[r] + bo;  // coalesced
    }
}

__global__ __launch_bounds__(256) void logits_kernel(
    const int* __restrict__ dest, const int* __restrict__ tt,
    const int* __restrict__ candidates,
    const float* __restrict__ dense_w, const float* __restrict__ dense_b,
    const float* __restrict__ cand_w, const float* __restrict__ cand_b,
    const float* __restrict__ segs_src, const float* __restrict__ segs_trg,
    const float* __restrict__ traffic_pop,
    const float* __restrict__ out_ws,
    float* __restrict__ logits)
{
    const int b = blockIdx.x;
    const int tid = threadIdx.x;
    const int wave = tid >> 6;
    const int lane = tid & 63;
    const int mbase = wave * 16;   // 4 waves x 16 candidates

    // ---- dense-dot fragment: lane l (0..62) holds out[b, 4l..4l+3]; lane 63 zeroed ----
    const int ll = (lane < 63) ? lane : 62;        // clamp keeps address in-bounds
    float4 o4 = *(const float4*)(out_ws + (size_t)b * DM8 + ll * 4);
    if (lane == 63) { o4.x = 0.f; o4.y = 0.f; o4.z = 0.f; o4.w = 0.f; }

    // ---- phase 0: lanes 0..15 precompute tail[m] + dense_b for this wave's candidates ----
    float tail = 0.f;
    int candv = 0;
    if (lane < 16) {
        const int m = mbase + lane;
        candv = candidates[b * NCAND + m];
        const float4 t4 = *(const float4*)(out_ws + (size_t)b * DM8 + DWC); // out[252:256] (bcast)
        const int db = dest[b];
        const float2 dsx = *(const float2*)(segs_src + 2 * (size_t)db);
        const float2 sx = *(const float2*)(segs_src + 2 * (size_t)candv);
        const float2 tx = *(const float2*)(segs_trg + 2 * (size_t)candv);
        const float v1x = dsx.x - sx.x, v1y = dsx.y - sx.y;
        const float v2x = tx.x - sx.x, v2y = tx.y - sx.y;
        const float num = v1x * v2x + v1y * v2y;
        const float den = fmaxf(sqrtf(v1x * v1x + v1y * v1y) *
                                sqrtf(v2x * v2x + v2y * v2y), 1e-8f);
        const float cosv = num / den;
        const float tf = traffic_pop[(size_t)candv * TSLOTS + tt[b]];
        const float e0 = fmaf(cosv, cand_w[0], fmaf(tf, cand_w[1], cand_b[0]));
        const float e1 = fmaf(cosv, cand_w[2], fmaf(tf, cand_w[3], cand_b[1]));
        const float e2 = fmaf(cosv, cand_w[4], fmaf(tf, cand_w[5], cand_b[2]));
        const float e3 = fmaf(cosv, cand_w[6], fmaf(tf, cand_w[7], cand_b[3]));
        tail = e0 * t4.x + e1 * t4.y + e2 * t4.z + e3 * t4.w + dense_b[candv];
    }

    // ---- phase 1: 4x-unrolled branch-free candidate loop ----
    for (int mi = 0; mi < 16; mi += 4) {
        const int c0 = __shfl(candv, mi + 0, 64);
        const int c1 = __shfl(candv, mi + 1, 64);
        const int c2 = __shfl(candv, mi + 2, 64);
        const int c3 = __shfl(candv, mi + 3, 64);
        const float4 dw0 = *(const float4*)(dense_w + (size_t)c0 * DWC + ll * 4);
        const float4 dw1 = *(const float4*)(dense_w + (size_t)c1 * DWC + ll * 4);
        const float4 dw2 = *(const float4*)(dense_w + (size_t)c2 * DWC + ll * 4);
        const float4 dw3 = *(const float4*)(dense_w + (size_t)c3 * DWC + ll * 4);
        float p0 = dw0.x * o4.x + dw0.y * o4.y + dw0.z * o4.z + dw0.w * o4.w;
        float p1 = dw1.x * o4.x + dw1.y * o4.y + dw1.z * o4.z + dw1.w * o4.w;
        float p2 = dw2.x * o4.x + dw2.y * o4.y + dw2.z * o4.z + dw2.w * o4.w;
        float p3 = dw3.x * o4.x + dw3.y * o4.y + dw3.z * o4.z + dw3.w * o4.w;
        const float t0 = __shfl(tail, mi + 0, 64);
        const float t1 = __shfl(tail, mi + 1, 64);
        const float t2 = __shfl(tail, mi + 2, 64);
        const float t3 = __shfl(tail, mi + 3, 64);
#pragma unroll
        for (int s = 1; s < 64; s <<= 1) {   // 4 interleaved butterflies -> 4x ILP
            p0 += __shfl_xor(p0, s, 64);
            p1 += __shfl_xor(p1, s, 64);
            p2 += __shfl_xor(p2, s, 64);
            p3 += __shfl_xor(p3, s, 64);
        }
        if (lane == 0) {
            float4 res;
            res.x = p0 + t0; res.y = p1 + t1; res.z = p2 + t2; res.w = p3 + t3;
            *(float4*)(logits + (size_t)b * NCAND + mbase + mi) = res;
        }
    }
}

extern "C" void kernel_launch(void* const* d_in, const int* in_sizes, int n_in,
                              void* d_out, int out_size, void* d_ws, size_t ws_size,
                              hipStream_t stream) {
    const int*   src         = (const int*)d_in[0];
    const int*   dest        = (const int*)d_in[1];
    const int*   tt          = (const int*)d_in[2];
    const int*   candidates  = (const int*)d_in[3];
    const float* offset      = (const float*)d_in[4];
    const float* emb_feat    = (const float*)d_in[5];
    const float* emb_dest    = (const float*)d_in[6];
    const float* w1          = (const float*)d_in[7];
    const float* b1          = (const float*)d_in[8];
    const float* bn_gamma    = (const float*)d_in[9];
    const float* bn_beta     = (const float*)d_in[10];
    const float* bn_mean     = (const float*)d_in[11];
    const float* bn_var      = (const float*)d_in[12];
    const float* w2          = (const float*)d_in[13];
    const float* b2          = (const float*)d_in[14];
    const float* dense_w     = (const float*)d_in[15];
    const float* dense_b     = (const float*)d_in[16];
    const float* cand_w      = (const float*)d_in[17];
    const float* cand_b      = (const float*)d_in[18];
    const float* segs_src    = (const float*)d_in[19];
    const float* segs_trg    = (const float*)d_in[20];
    const float* traffic_pop = (const float*)d_in[21];

    float* out_ws = (float*)d_ws;           // 4096*256 f32 = 4 MB scratch
    float* logits = (float*)d_out;          // 4096*64 f32

    mlp_kernel<<<BATCH / TROWS, 256, 0, stream>>>(
        src, dest, offset, emb_feat, emb_dest,
        w1, b1, bn_gamma, bn_beta, bn_mean, bn_var, w2, b2, out_ws);

    logits_kernel<<<BATCH, 256, 0, stream>>>(
        dest, tt, candidates, dense_w, dense_b, cand_w, cand_b,
        segs_src, segs_trg, traffic_pop, out_ws, logits);
}

// Round 3
// 90.214 us; speedup vs baseline: 1.7388x; 1.7388x over previous
//
#include <hip/hip_runtime.h>

// KeySegPred — round 3: MLP via bf16 MFMA (16x16x32), logits kernel unchanged.
// mlp_mfma_kernel: per block = 16 batch rows, 8 waves.
//   GEMM1: C1[16][512] = code[16][256]@w1[:, :256]^T  (bf16 MFMA, 8 k-steps)
//          + fp32 rank-2 update for the 2 offset columns (exact)
//          + bias + BN + ReLU  -> hlds bf16 [16][520]
//   GEMM2: out[16][256] = h[16][512]@w2^T (bf16 MFMA, 16 k-steps) + b2 -> out_ws fp32
// logits_kernel: identical to round 2 (~45 us measured).

#define BATCH 4096
#define DSEG 128
#define DS_ 258
#define DM7 512
#define DM8 256
#define NCAND 64
#define DWC 252
#define TSLOTS 96

typedef short bf16x8 __attribute__((ext_vector_type(8)));
typedef float f32x4 __attribute__((ext_vector_type(4)));

static __device__ __forceinline__ short f2bf(float f) {
    union { float f; unsigned u; } v; v.f = f;
    unsigned r = (v.u + 0x7FFFu + ((v.u >> 16) & 1u)) >> 16;  // RNE
    return (short)r;
}

__global__ __launch_bounds__(512) void mlp_mfma_kernel(
    const int* __restrict__ src, const int* __restrict__ dest,
    const float* __restrict__ offset,
    const float* __restrict__ emb_feat, const float* __restrict__ emb_dest,
    const float* __restrict__ w1, const float* __restrict__ b1,
    const float* __restrict__ bn_gamma, const float* __restrict__ bn_beta,
    const float* __restrict__ bn_mean, const float* __restrict__ bn_var,
    const float* __restrict__ w2, const float* __restrict__ b2,
    float* __restrict__ out_ws)
{
    __shared__ __align__(16) short hlds[16][520];   // bf16 h, row stride 1040B (16B-aligned)
    const int tid = threadIdx.x;
    const int w    = tid >> 6;     // wave 0..7
    const int lane = tid & 63;
    const int lg   = lane >> 4;    // 0..3 (k-group / acc row group)
    const int lr   = lane & 15;    // 0..15 (A row / B col)
    const int b0   = blockIdx.x * 16;

    // ---- A fragments for GEMM1: code rows gathered straight from tables ----
    const int si = src[b0 + lr];
    const int di = dest[b0 + lr];
    const float* fb = emb_feat + (size_t)si * DSEG;
    const float* db = emb_dest + (size_t)di * DSEG;
    bf16x8 a1[8];
#pragma unroll
    for (int s = 0; s < 8; ++s) {
        const float* p = (s < 4) ? (fb + s * 32 + lg * 8)
                                 : (db + (s - 4) * 32 + lg * 8);
        const float4 x = *(const float4*)p;
        const float4 y = *(const float4*)(p + 4);
        bf16x8 t;
        t[0] = f2bf(x.x); t[1] = f2bf(x.y); t[2] = f2bf(x.z); t[3] = f2bf(x.w);
        t[4] = f2bf(y.x); t[5] = f2bf(y.y); t[6] = f2bf(y.z); t[7] = f2bf(y.w);
        a1[s] = t;
    }
    // offset features for the 4 acc rows this lane covers (m = lg*4+q) — kept exact fp32
    float off1[4], off2[4];
#pragma unroll
    for (int q = 0; q < 4; ++q) {
        const float4 o = *(const float4*)(offset + (size_t)(b0 + lg * 4 + q) * 4);
        off1[q] = o.y; off2[q] = o.z;
    }

    // ---- GEMM1 (+rank-2 +bias +BN +ReLU) -> hlds ----
#pragma unroll
    for (int nt = 0; nt < 4; ++nt) {
        const int n = (w * 4 + nt) * 16 + lr;        // this lane's w1 row / h col
        const float* wrow = w1 + (size_t)n * DS_;    // 8B-aligned (1032B rows)
        f32x4 acc = {0.f, 0.f, 0.f, 0.f};
#pragma unroll
        for (int s = 0; s < 8; ++s) {
            const float* p = wrow + s * 32 + lg * 8;
            const float2 x0 = *(const float2*)(p);
            const float2 x1 = *(const float2*)(p + 2);
            const float2 x2 = *(const float2*)(p + 4);
            const float2 x3 = *(const float2*)(p + 6);
            bf16x8 bb;
            bb[0] = f2bf(x0.x); bb[1] = f2bf(x0.y); bb[2] = f2bf(x1.x); bb[3] = f2bf(x1.y);
            bb[4] = f2bf(x2.x); bb[5] = f2bf(x2.y); bb[6] = f2bf(x3.x); bb[7] = f2bf(x3.y);
            acc = __builtin_amdgcn_mfma_f32_16x16x32_bf16(a1[s], bb, acc, 0, 0, 0);
        }
        const float2 wtail = *(const float2*)(wrow + 256);   // w1[n][256..257]
        const float scale = bn_gamma[n] / sqrtf(bn_var[n] + 1e-6f);
        const float shift = bn_beta[n] - bn_mean[n] * scale;
        const float bias  = b1[n];
#pragma unroll
        for (int q = 0; q < 4; ++q) {
            float v = acc[q] + bias + off1[q] * wtail.x + off2[q] * wtail.y;
            v = fmaf(v, scale, shift);
            v = fmaxf(v, 0.f);
            hlds[lg * 4 + q][n] = f2bf(v);
        }
    }
    __syncthreads();

    // ---- GEMM2: A fragments from hlds (hoisted, reused across n-tiles) ----
    bf16x8 a2[16];
#pragma unroll
    for (int s = 0; s < 16; ++s) {
        a2[s] = *(const bf16x8*)&hlds[lr][s * 32 + lg * 8];   // 16B-aligned ds_read_b128
    }
#pragma unroll
    for (int nt = 0; nt < 2; ++nt) {
        const int n = (w * 2 + nt) * 16 + lr;        // this lane's w2 row / out col
        const float* wrow = w2 + (size_t)n * DM7;    // 2048B rows, 16B-aligned
        f32x4 acc = {0.f, 0.f, 0.f, 0.f};
#pragma unroll
        for (int s = 0; s < 16; ++s) {
            const float4 x = *(const float4*)(wrow + s * 32 + lg * 8);
            const float4 y = *(const float4*)(wrow + s * 32 + lg * 8 + 4);
            bf16x8 bb;
            bb[0] = f2bf(x.x); bb[1] = f2bf(x.y); bb[2] = f2bf(x.z); bb[3] = f2bf(x.w);
            bb[4] = f2bf(y.x); bb[5] = f2bf(y.y); bb[6] = f2bf(y.z); bb[7] = f2bf(y.w);
            acc = __builtin_amdgcn_mfma_f32_16x16x32_bf16(a2[s], bb, acc, 0, 0, 0);
        }
        const float bias = b2[n];
#pragma unroll
        for (int q = 0; q < 4; ++q) {
            out_ws[(size_t)(b0 + lg * 4 + q) * DM8 + n] = acc[q] + bias;
        }
    }
}

__global__ __launch_bounds__(256) void logits_kernel(
    const int* __restrict__ dest, const int* __restrict__ tt,
    const int* __restrict__ candidates,
    const float* __restrict__ dense_w, const float* __restrict__ dense_b,
    const float* __restrict__ cand_w, const float* __restrict__ cand_b,
    const float* __restrict__ segs_src, const float* __restrict__ segs_trg,
    const float* __restrict__ traffic_pop,
    const float* __restrict__ out_ws,
    float* __restrict__ logits)
{
    const int b = blockIdx.x;
    const int tid = threadIdx.x;
    const int wave = tid >> 6;
    const int lane = tid & 63;
    const int mbase = wave * 16;   // 4 waves x 16 candidates

    // ---- dense-dot fragment: lane l (0..62) holds out[b, 4l..4l+3]; lane 63 zeroed ----
    const int ll = (lane < 63) ? lane : 62;        // clamp keeps address in-bounds
    float4 o4 = *(const float4*)(out_ws + (size_t)b * DM8 + ll * 4);
    if (lane == 63) { o4.x = 0.f; o4.y = 0.f; o4.z = 0.f; o4.w = 0.f; }

    // ---- phase 0: lanes 0..15 precompute tail[m] + dense_b for this wave's candidates ----
    float tail = 0.f;
    int candv = 0;
    if (lane < 16) {
        const int m = mbase + lane;
        candv = candidates[b * NCAND + m];
        const float4 t4 = *(const float4*)(out_ws + (size_t)b * DM8 + DWC); // out[252:256]
        const int db = dest[b];
        const float2 dsx = *(const float2*)(segs_src + 2 * (size_t)db);
        const float2 sx = *(const float2*)(segs_src + 2 * (size_t)candv);
        const float2 tx = *(const float2*)(segs_trg + 2 * (size_t)candv);
        const float v1x = dsx.x - sx.x, v1y = dsx.y - sx.y;
        const float v2x = tx.x - sx.x, v2y = tx.y - sx.y;
        const float num = v1x * v2x + v1y * v2y;
        const float den = fmaxf(sqrtf(v1x * v1x + v1y * v1y) *
                                sqrtf(v2x * v2x + v2y * v2y), 1e-8f);
        const float cosv = num / den;
        const float tf = traffic_pop[(size_t)candv * TSLOTS + tt[b]];
        const float e0 = fmaf(cosv, cand_w[0], fmaf(tf, cand_w[1], cand_b[0]));
        const float e1 = fmaf(cosv, cand_w[2], fmaf(tf, cand_w[3], cand_b[1]));
        const float e2 = fmaf(cosv, cand_w[4], fmaf(tf, cand_w[5], cand_b[2]));
        const float e3 = fmaf(cosv, cand_w[6], fmaf(tf, cand_w[7], cand_b[3]));
        tail = e0 * t4.x + e1 * t4.y + e2 * t4.z + e3 * t4.w + dense_b[candv];
    }

    // ---- phase 1: 4x-unrolled branch-free candidate loop ----
    for (int mi = 0; mi < 16; mi += 4) {
        const int c0 = __shfl(candv, mi + 0, 64);
        const int c1 = __shfl(candv, mi + 1, 64);
        const int c2 = __shfl(candv, mi + 2, 64);
        const int c3 = __shfl(candv, mi + 3, 64);
        const float4 dw0 = *(const float4*)(dense_w + (size_t)c0 * DWC + ll * 4);
        const float4 dw1 = *(const float4*)(dense_w + (size_t)c1 * DWC + ll * 4);
        const float4 dw2 = *(const float4*)(dense_w + (size_t)c2 * DWC + ll * 4);
        const float4 dw3 = *(const float4*)(dense_w + (size_t)c3 * DWC + ll * 4);
        float p0 = dw0.x * o4.x + dw0.y * o4.y + dw0.z * o4.z + dw0.w * o4.w;
        float p1 = dw1.x * o4.x + dw1.y * o4.y + dw1.z * o4.z + dw1.w * o4.w;
        float p2 = dw2.x * o4.x + dw2.y * o4.y + dw2.z * o4.z + dw2.w * o4.w;
        float p3 = dw3.x * o4.x + dw3.y * o4.y + dw3.z * o4.z + dw3.w * o4.w;
        const float t0 = __shfl(tail, mi + 0, 64);
        const float t1 = __shfl(tail, mi + 1, 64);
        const float t2 = __shfl(tail, mi + 2, 64);
        const float t3 = __shfl(tail, mi + 3, 64);
#pragma unroll
        for (int s = 1; s < 64; s <<= 1) {   // 4 interleaved butterflies -> 4x ILP
            p0 += __shfl_xor(p0, s, 64);
            p1 += __shfl_xor(p1, s, 64);
            p2 += __shfl_xor(p2, s, 64);
            p3 += __shfl_xor(p3, s, 64);
        }
        if (lane == 0) {
            float4 res;
            res.x = p0 + t0; res.y = p1 + t1; res.z = p2 + t2; res.w = p3 + t3;
            *(float4*)(logits + (size_t)b * NCAND + mbase + mi) = res;
        }
    }
}

extern "C" void kernel_launch(void* const* d_in, const int* in_sizes, int n_in,
                              void* d_out, int out_size, void* d_ws, size_t ws_size,
                              hipStream_t stream) {
    const int*   src         = (const int*)d_in[0];
    const int*   dest        = (const int*)d_in[1];
    const int*   tt          = (const int*)d_in[2];
    const int*   candidates  = (const int*)d_in[3];
    const float* offset      = (const float*)d_in[4];
    const float* emb_feat    = (const float*)d_in[5];
    const float* emb_dest    = (const float*)d_in[6];
    const float* w1          = (const float*)d_in[7];
    const float* b1          = (const float*)d_in[8];
    const float* bn_gamma    = (const float*)d_in[9];
    const float* bn_beta     = (const float*)d_in[10];
    const float* bn_mean     = (const float*)d_in[11];
    const float* bn_var      = (const float*)d_in[12];
    const float* w2          = (const float*)d_in[13];
    const float* b2          = (const float*)d_in[14];
    const float* dense_w     = (const float*)d_in[15];
    const float* dense_b     = (const float*)d_in[16];
    const float* cand_w      = (const float*)d_in[17];
    const float* cand_b      = (const float*)d_in[18];
    const float* segs_src    = (const float*)d_in[19];
    const float* segs_trg    = (const float*)d_in[20];
    const float* traffic_pop = (const float*)d_in[21];

    float* out_ws = (float*)d_ws;           // 4096*256 f32 = 4 MB scratch
    float* logits = (float*)d_out;          // 4096*64 f32

    mlp_mfma_kernel<<<BATCH / 16, 512, 0, stream>>>(
        src, dest, offset, emb_feat, emb_dest,
        w1, b1, bn_gamma, bn_beta, bn_mean, bn_var, w2, b2, out_ws);

    logits_kernel<<<BATCH, 256, 0, stream>>>(
        dest, tt, candidates, dense_w, dense_b, cand_w, cand_b,
        segs_src, segs_trg, traffic_pop, out_ws, logits);
}

// Round 4
// 89.276 us; speedup vs baseline: 1.7570x; 1.0105x over previous
//
#include <hip/hip_runtime.h>

// KeySegPred — round 4: logits with 16-deep gather pipeline + LDS transpose-reduce.
// mlp_mfma_kernel: unchanged from round 3 (~24 us).
// logits_kernel (per block = one batch row b, 4 waves x 16 candidates):
//   1. load candidate ids, broadcast, issue ALL 16 dense_w row-gathers (dwordx4, 16 in flight)
//   2. tail math (cos/traffic features) overlapped under the gathers
//   3. 16 per-lane dot partials -> plds[wave][cand][67] -> per-lane 16-sum + 2 shfl_xor

#define BATCH 4096
#define DSEG 128
#define DS_ 258
#define DM7 512
#define DM8 256
#define NCAND 64
#define DWC 252
#define TSLOTS 96

typedef short bf16x8 __attribute__((ext_vector_type(8)));
typedef float f32x4 __attribute__((ext_vector_type(4)));

static __device__ __forceinline__ short f2bf(float f) {
    union { float f; unsigned u; } v; v.f = f;
    unsigned r = (v.u + 0x7FFFu + ((v.u >> 16) & 1u)) >> 16;  // RNE
    return (short)r;
}

__global__ __launch_bounds__(512) void mlp_mfma_kernel(
    const int* __restrict__ src, const int* __restrict__ dest,
    const float* __restrict__ offset,
    const float* __restrict__ emb_feat, const float* __restrict__ emb_dest,
    const float* __restrict__ w1, const float* __restrict__ b1,
    const float* __restrict__ bn_gamma, const float* __restrict__ bn_beta,
    const float* __restrict__ bn_mean, const float* __restrict__ bn_var,
    const float* __restrict__ w2, const float* __restrict__ b2,
    float* __restrict__ out_ws)
{
    __shared__ __align__(16) short hlds[16][520];   // bf16 h, row stride 1040B (16B-aligned)
    const int tid = threadIdx.x;
    const int w    = tid >> 6;     // wave 0..7
    const int lane = tid & 63;
    const int lg   = lane >> 4;    // 0..3 (k-group / acc row group)
    const int lr   = lane & 15;    // 0..15 (A row / B col)
    const int b0   = blockIdx.x * 16;

    // ---- A fragments for GEMM1: code rows gathered straight from tables ----
    const int si = src[b0 + lr];
    const int di = dest[b0 + lr];
    const float* fb = emb_feat + (size_t)si * DSEG;
    const float* db = emb_dest + (size_t)di * DSEG;
    bf16x8 a1[8];
#pragma unroll
    for (int s = 0; s < 8; ++s) {
        const float* p = (s < 4) ? (fb + s * 32 + lg * 8)
                                 : (db + (s - 4) * 32 + lg * 8);
        const float4 x = *(const float4*)p;
        const float4 y = *(const float4*)(p + 4);
        bf16x8 t;
        t[0] = f2bf(x.x); t[1] = f2bf(x.y); t[2] = f2bf(x.z); t[3] = f2bf(x.w);
        t[4] = f2bf(y.x); t[5] = f2bf(y.y); t[6] = f2bf(y.z); t[7] = f2bf(y.w);
        a1[s] = t;
    }
    // offset features for the 4 acc rows this lane covers (m = lg*4+q) — kept exact fp32
    float off1[4], off2[4];
#pragma unroll
    for (int q = 0; q < 4; ++q) {
        const float4 o = *(const float4*)(offset + (size_t)(b0 + lg * 4 + q) * 4);
        off1[q] = o.y; off2[q] = o.z;
    }

    // ---- GEMM1 (+rank-2 +bias +BN +ReLU) -> hlds ----
#pragma unroll
    for (int nt = 0; nt < 4; ++nt) {
        const int n = (w * 4 + nt) * 16 + lr;        // this lane's w1 row / h col
        const float* wrow = w1 + (size_t)n * DS_;    // 8B-aligned (1032B rows)
        f32x4 acc = {0.f, 0.f, 0.f, 0.f};
#pragma unroll
        for (int s = 0; s < 8; ++s) {
            const float* p = wrow + s * 32 + lg * 8;
            const float2 x0 = *(const float2*)(p);
            const float2 x1 = *(const float2*)(p + 2);
            const float2 x2 = *(const float2*)(p + 4);
            const float2 x3 = *(const float2*)(p + 6);
            bf16x8 bb;
            bb[0] = f2bf(x0.x); bb[1] = f2bf(x0.y); bb[2] = f2bf(x1.x); bb[3] = f2bf(x1.y);
            bb[4] = f2bf(x2.x); bb[5] = f2bf(x2.y); bb[6] = f2bf(x3.x); bb[7] = f2bf(x3.y);
            acc = __builtin_amdgcn_mfma_f32_16x16x32_bf16(a1[s], bb, acc, 0, 0, 0);
        }
        const float2 wtail = *(const float2*)(wrow + 256);   // w1[n][256..257]
        const float scale = bn_gamma[n] / sqrtf(bn_var[n] + 1e-6f);
        const float shift = bn_beta[n] - bn_mean[n] * scale;
        const float bias  = b1[n];
#pragma unroll
        for (int q = 0; q < 4; ++q) {
            float v = acc[q] + bias + off1[q] * wtail.x + off2[q] * wtail.y;
            v = fmaf(v, scale, shift);
            v = fmaxf(v, 0.f);
            hlds[lg * 4 + q][n] = f2bf(v);
        }
    }
    __syncthreads();

    // ---- GEMM2: A fragments from hlds (hoisted, reused across n-tiles) ----
    bf16x8 a2[16];
#pragma unroll
    for (int s = 0; s < 16; ++s) {
        a2[s] = *(const bf16x8*)&hlds[lr][s * 32 + lg * 8];   // 16B-aligned ds_read_b128
    }
#pragma unroll
    for (int nt = 0; nt < 2; ++nt) {
        const int n = (w * 2 + nt) * 16 + lr;        // this lane's w2 row / out col
        const float* wrow = w2 + (size_t)n * DM7;    // 2048B rows, 16B-aligned
        f32x4 acc = {0.f, 0.f, 0.f, 0.f};
#pragma unroll
        for (int s = 0; s < 16; ++s) {
            const float4 x = *(const float4*)(wrow + s * 32 + lg * 8);
            const float4 y = *(const float4*)(wrow + s * 32 + lg * 8 + 4);
            bf16x8 bb;
            bb[0] = f2bf(x.x); bb[1] = f2bf(x.y); bb[2] = f2bf(x.z); bb[3] = f2bf(x.w);
            bb[4] = f2bf(y.x); bb[5] = f2bf(y.y); bb[6] = f2bf(y.z); bb[7] = f2bf(y.w);
            acc = __builtin_amdgcn_mfma_f32_16x16x32_bf16(a2[s], bb, acc, 0, 0, 0);
        }
        const float bias = b2[n];
#pragma unroll
        for (int q = 0; q < 4; ++q) {
            out_ws[(size_t)(b0 + lg * 4 + q) * DM8 + n] = acc[q] + bias;
        }
    }
}

__global__ __launch_bounds__(256) void logits_kernel(
    const int* __restrict__ dest, const int* __restrict__ tt,
    const int* __restrict__ candidates,
    const float* __restrict__ dense_w, const float* __restrict__ dense_b,
    const float* __restrict__ cand_w, const float* __restrict__ cand_b,
    const float* __restrict__ segs_src, const float* __restrict__ segs_trg,
    const float* __restrict__ traffic_pop,
    const float* __restrict__ out_ws,
    float* __restrict__ logits)
{
    __shared__ float plds[4][16][67];   // pad 67 -> <=2-way LDS banks on strided reads
    const int b = blockIdx.x;
    const int tid = threadIdx.x;
    const int wave = tid >> 6;
    const int lane = tid & 63;
    const int mbase = wave * 16;   // 4 waves x 16 candidates

    // ---- candidate ids first so gathers can be issued ASAP ----
    int candv = 0;
    if (lane < 16) candv = candidates[b * NCAND + mbase + lane];

    // ---- issue ALL 16 dense_w row gathers (uniform base per i, 16 in flight) ----
    const int ll = (lane < 63) ? lane : 62;        // clamp keeps address in-bounds
    float4 dw[16];
#pragma unroll
    for (int i = 0; i < 16; ++i) {
        const int ci = __shfl(candv, i, 64);       // readlane broadcast
        dw[i] = *(const float4*)(dense_w + (size_t)ci * DWC + ll * 4);
    }

    // ---- out fragment: lane l (0..62) holds out[b, 4l..4l+3]; lane 63 zeroed ----
    float4 o4 = *(const float4*)(out_ws + (size_t)b * DM8 + ll * 4);
    if (lane == 63) { o4.x = 0.f; o4.y = 0.f; o4.z = 0.f; o4.w = 0.f; }

    // ---- tail math (cos + traffic + dense_b), overlapped under the gathers ----
    float tail = 0.f;
    if (lane < 16) {
        const float4 t4 = *(const float4*)(out_ws + (size_t)b * DM8 + DWC); // out[252:256]
        const int db = dest[b];
        const float2 dsx = *(const float2*)(segs_src + 2 * (size_t)db);
        const float2 sx = *(const float2*)(segs_src + 2 * (size_t)candv);
        const float2 tx = *(const float2*)(segs_trg + 2 * (size_t)candv);
        const float v1x = dsx.x - sx.x, v1y = dsx.y - sx.y;
        const float v2x = tx.x - sx.x, v2y = tx.y - sx.y;
        const float num = v1x * v2x + v1y * v2y;
        const float den = fmaxf(sqrtf(v1x * v1x + v1y * v1y) *
                                sqrtf(v2x * v2x + v2y * v2y), 1e-8f);
        const float cosv = num / den;
        const float tf = traffic_pop[(size_t)candv * TSLOTS + tt[b]];
        const float e0 = fmaf(cosv, cand_w[0], fmaf(tf, cand_w[1], cand_b[0]));
        const float e1 = fmaf(cosv, cand_w[2], fmaf(tf, cand_w[3], cand_b[1]));
        const float e2 = fmaf(cosv, cand_w[4], fmaf(tf, cand_w[5], cand_b[2]));
        const float e3 = fmaf(cosv, cand_w[6], fmaf(tf, cand_w[7], cand_b[3]));
        tail = e0 * t4.x + e1 * t4.y + e2 * t4.z + e3 * t4.w + dense_b[candv];
    }

    // ---- per-lane dot partials -> LDS ----
#pragma unroll
    for (int i = 0; i < 16; ++i) {
        const float p = dw[i].x * o4.x + dw[i].y * o4.y + dw[i].z * o4.z + dw[i].w * o4.w;
        plds[wave][i][lane] = p;
    }
    __syncthreads();

    // ---- transpose-reduce: lane -> (candidate cc, quarter qq) ----
    const int cc = lane >> 2;
    const int qq = lane & 3;
    float s = 0.f;
#pragma unroll
    for (int j = 0; j < 16; ++j) s += plds[wave][cc][qq * 16 + j];
    s += __shfl_xor(s, 1, 64);
    s += __shfl_xor(s, 2, 64);
    const float tl = __shfl(tail, cc, 64);
    if (qq == 0) logits[(size_t)b * NCAND + mbase + cc] = s + tl;
}

extern "C" void kernel_launch(void* const* d_in, const int* in_sizes, int n_in,
                              void* d_out, int out_size, void* d_ws, size_t ws_size,
                              hipStream_t stream) {
    const int*   src         = (const int*)d_in[0];
    const int*   dest        = (const int*)d_in[1];
    const int*   tt          = (const int*)d_in[2];
    const int*   candidates  = (const int*)d_in[3];
    const float* offset      = (const float*)d_in[4];
    const float* emb_feat    = (const float*)d_in[5];
    const float* emb_dest    = (const float*)d_in[6];
    const float* w1          = (const float*)d_in[7];
    const float* b1          = (const float*)d_in[8];
    const float* bn_gamma    = (const float*)d_in[9];
    const float* bn_beta     = (const float*)d_in[10];
    const float* bn_mean     = (const float*)d_in[11];
    const float* bn_var      = (const float*)d_in[12];
    const float* w2          = (const float*)d_in[13];
    const float* b2          = (const float*)d_in[14];
    const float* dense_w     = (const float*)d_in[15];
    const float* dense_b     = (const float*)d_in[16];
    const float* cand_w      = (const float*)d_in[17];
    const float* cand_b      = (const float*)d_in[18];
    const float* segs_src    = (const float*)d_in[19];
    const float* segs_trg    = (const float*)d_in[20];
    const float* traffic_pop = (const float*)d_in[21];

    float* out_ws = (float*)d_ws;           // 4096*256 f32 = 4 MB scratch
    float* logits = (float*)d_out;          // 4096*64 f32

    mlp_mfma_kernel<<<BATCH / 16, 512, 0, stream>>>(
        src, dest, offset, emb_feat, emb_dest,
        w1, b1, bn_gamma, bn_beta, bn_mean, bn_var, w2, b2, out_ws);

    logits_kernel<<<BATCH, 256, 0, stream>>>(
        dest, tt, candidates, dense_w, dense_b, cand_w, cand_b,
        segs_src, segs_trg, traffic_pop, out_ws, logits);
}

// Round 5
// 86.391 us; speedup vs baseline: 1.8157x; 1.0334x over previous
//
#include <hip/hip_runtime.h>

// KeySegPred — round 5: bf16 dense_w table (gather bytes /2), conversion hidden
// under the MLP phase via block-role split.
//   Kernel 1 (mlp_conv_kernel, 512 blocks x 512 thr):
//     blocks 0..255   : MFMA MLP (identical math to round 4) -> out_ws fp32
//     blocks 256..511 : stream-convert dense_w fp32 -> bf16 table in d_ws
//   Kernel 2 (logits_bf16_kernel): round-4 structure, 8B/lane bf16 row gathers.
//   Fallback (ws too small): round-4 fp32 logits path.

#define BATCH 4096
#define DSEG 128
#define DS_ 258
#define DM7 512
#define DM8 256
#define NCAND 64
#define DWC 252
#define TSLOTS 96
#define SEGN 100000

typedef short bf16x8 __attribute__((ext_vector_type(8)));
typedef short bf16x4 __attribute__((ext_vector_type(4)));
typedef float f32x4 __attribute__((ext_vector_type(4)));

static __device__ __forceinline__ short f2bf(float f) {
    union { float f; unsigned u; } v; v.f = f;
    unsigned r = (v.u + 0x7FFFu + ((v.u >> 16) & 1u)) >> 16;  // RNE
    return (short)r;
}
static __device__ __forceinline__ float bfu2f(unsigned u16hi) {  // arg: bf16 in low 16
    union { unsigned u; float f; } v; v.u = u16hi << 16; return v.f;
}

__global__ __launch_bounds__(512) void mlp_conv_kernel(
    const int* __restrict__ src, const int* __restrict__ dest,
    const float* __restrict__ offset,
    const float* __restrict__ emb_feat, const float* __restrict__ emb_dest,
    const float* __restrict__ w1, const float* __restrict__ b1,
    const float* __restrict__ bn_gamma, const float* __restrict__ bn_beta,
    const float* __restrict__ bn_mean, const float* __restrict__ bn_var,
    const float* __restrict__ w2, const float* __restrict__ b2,
    const float* __restrict__ dense_w, short* __restrict__ wtab,
    float* __restrict__ out_ws)
{
    const int tid = threadIdx.x;

    if (blockIdx.x >= BATCH / 16) {
        // ---- conversion role: dense_w (25.2M f32) -> wtab (bf16) ----
        const size_t nthr = (size_t)(gridDim.x - BATCH / 16) * 512;
        const size_t g0 = (size_t)(blockIdx.x - BATCH / 16) * 512 + tid;
        const float4* __restrict__ src4 = (const float4*)dense_w;
        bf16x4* __restrict__ dst4 = (bf16x4*)wtab;
        const size_t n4 = (size_t)SEGN * DWC / 4;   // 6,300,000
        for (size_t i = g0; i < n4; i += nthr) {
            const float4 v = src4[i];
            bf16x4 s;
            s[0] = f2bf(v.x); s[1] = f2bf(v.y); s[2] = f2bf(v.z); s[3] = f2bf(v.w);
            dst4[i] = s;
        }
        return;
    }

    // ---- MLP role (identical math to round 4) ----
    __shared__ __align__(16) short hlds[16][520];
    const int w    = tid >> 6;     // wave 0..7
    const int lane = tid & 63;
    const int lg   = lane >> 4;    // 0..3
    const int lr   = lane & 15;    // 0..15
    const int b0   = blockIdx.x * 16;

    const int si = src[b0 + lr];
    const int di = dest[b0 + lr];
    const float* fb = emb_feat + (size_t)si * DSEG;
    const float* db = emb_dest + (size_t)di * DSEG;
    bf16x8 a1[8];
#pragma unroll
    for (int s = 0; s < 8; ++s) {
        const float* p = (s < 4) ? (fb + s * 32 + lg * 8)
                                 : (db + (s - 4) * 32 + lg * 8);
        const float4 x = *(const float4*)p;
        const float4 y = *(const float4*)(p + 4);
        bf16x8 t;
        t[0] = f2bf(x.x); t[1] = f2bf(x.y); t[2] = f2bf(x.z); t[3] = f2bf(x.w);
        t[4] = f2bf(y.x); t[5] = f2bf(y.y); t[6] = f2bf(y.z); t[7] = f2bf(y.w);
        a1[s] = t;
    }
    float off1[4], off2[4];
#pragma unroll
    for (int q = 0; q < 4; ++q) {
        const float4 o = *(const float4*)(offset + (size_t)(b0 + lg * 4 + q) * 4);
        off1[q] = o.y; off2[q] = o.z;
    }

#pragma unroll
    for (int nt = 0; nt < 4; ++nt) {
        const int n = (w * 4 + nt) * 16 + lr;
        const float* wrow = w1 + (size_t)n * DS_;
        f32x4 acc = {0.f, 0.f, 0.f, 0.f};
#pragma unroll
        for (int s = 0; s < 8; ++s) {
            const float* p = wrow + s * 32 + lg * 8;
            const float2 x0 = *(const float2*)(p);
            const float2 x1 = *(const float2*)(p + 2);
            const float2 x2 = *(const float2*)(p + 4);
            const float2 x3 = *(const float2*)(p + 6);
            bf16x8 bb;
            bb[0] = f2bf(x0.x); bb[1] = f2bf(x0.y); bb[2] = f2bf(x1.x); bb[3] = f2bf(x1.y);
            bb[4] = f2bf(x2.x); bb[5] = f2bf(x2.y); bb[6] = f2bf(x3.x); bb[7] = f2bf(x3.y);
            acc = __builtin_amdgcn_mfma_f32_16x16x32_bf16(a1[s], bb, acc, 0, 0, 0);
        }
        const float2 wtail = *(const float2*)(wrow + 256);
        const float scale = bn_gamma[n] / sqrtf(bn_var[n] + 1e-6f);
        const float shift = bn_beta[n] - bn_mean[n] * scale;
        const float bias  = b1[n];
#pragma unroll
        for (int q = 0; q < 4; ++q) {
            float v = acc[q] + bias + off1[q] * wtail.x + off2[q] * wtail.y;
            v = fmaf(v, scale, shift);
            v = fmaxf(v, 0.f);
            hlds[lg * 4 + q][n] = f2bf(v);
        }
    }
    __syncthreads();

    bf16x8 a2[16];
#pragma unroll
    for (int s = 0; s < 16; ++s) {
        a2[s] = *(const bf16x8*)&hlds[lr][s * 32 + lg * 8];
    }
#pragma unroll
    for (int nt = 0; nt < 2; ++nt) {
        const int n = (w * 2 + nt) * 16 + lr;
        const float* wrow = w2 + (size_t)n * DM7;
        f32x4 acc = {0.f, 0.f, 0.f, 0.f};
#pragma unroll
        for (int s = 0; s < 16; ++s) {
            const float4 x = *(const float4*)(wrow + s * 32 + lg * 8);
            const float4 y = *(const float4*)(wrow + s * 32 + lg * 8 + 4);
            bf16x8 bb;
            bb[0] = f2bf(x.x); bb[1] = f2bf(x.y); bb[2] = f2bf(x.z); bb[3] = f2bf(x.w);
            bb[4] = f2bf(y.x); bb[5] = f2bf(y.y); bb[6] = f2bf(y.z); bb[7] = f2bf(y.w);
            acc = __builtin_amdgcn_mfma_f32_16x16x32_bf16(a2[s], bb, acc, 0, 0, 0);
        }
        const float bias = b2[n];
#pragma unroll
        for (int q = 0; q < 4; ++q) {
            out_ws[(size_t)(b0 + lg * 4 + q) * DM8 + n] = acc[q] + bias;
        }
    }
}

template <bool BF16TAB>
__global__ __launch_bounds__(256) void logits_kernel_t(
    const int* __restrict__ dest, const int* __restrict__ tt,
    const int* __restrict__ candidates,
    const float* __restrict__ dense_w, const unsigned short* __restrict__ wtab,
    const float* __restrict__ dense_b,
    const float* __restrict__ cand_w, const float* __restrict__ cand_b,
    const float* __restrict__ segs_src, const float* __restrict__ segs_trg,
    const float* __restrict__ traffic_pop,
    const float* __restrict__ out_ws,
    float* __restrict__ logits)
{
    __shared__ float plds[4][16][67];
    const int b = blockIdx.x;
    const int tid = threadIdx.x;
    const int wave = tid >> 6;
    const int lane = tid & 63;
    const int mbase = wave * 16;

    int candv = 0;
    if (lane < 16) candv = candidates[b * NCAND + mbase + lane];

    const int ll = (lane < 63) ? lane : 62;
    float4 dwf[16];
    uint2  dwb[16];
    if (BF16TAB) {
#pragma unroll
        for (int i = 0; i < 16; ++i) {
            const int ci = __shfl(candv, i, 64);
            dwb[i] = *(const uint2*)(wtab + (size_t)ci * DWC + ll * 4);  // 8B, 2x2 bf16
        }
    } else {
#pragma unroll
        for (int i = 0; i < 16; ++i) {
            const int ci = __shfl(candv, i, 64);
            dwf[i] = *(const float4*)(dense_w + (size_t)ci * DWC + ll * 4);
        }
    }

    float4 o4 = *(const float4*)(out_ws + (size_t)b * DM8 + ll * 4);
    if (lane == 63) { o4.x = 0.f; o4.y = 0.f; o4.z = 0.f; o4.w = 0.f; }

    float tail = 0.f;
    if (lane < 16) {
        const float4 t4 = *(const float4*)(out_ws + (size_t)b * DM8 + DWC);
        const int db = dest[b];
        const float2 dsx = *(const float2*)(segs_src + 2 * (size_t)db);
        const float2 sx = *(const float2*)(segs_src + 2 * (size_t)candv);
        const float2 tx = *(const float2*)(segs_trg + 2 * (size_t)candv);
        const float v1x = dsx.x - sx.x, v1y = dsx.y - sx.y;
        const float v2x = tx.x - sx.x, v2y = tx.y - sx.y;
        const float num = v1x * v2x + v1y * v2y;
        const float den = fmaxf(sqrtf(v1x * v1x + v1y * v1y) *
                                sqrtf(v2x * v2x + v2y * v2y), 1e-8f);
        const float cosv = num / den;
        const float tf = traffic_pop[(size_t)candv * TSLOTS + tt[b]];
        const float e0 = fmaf(cosv, cand_w[0], fmaf(tf, cand_w[1], cand_b[0]));
        const float e1 = fmaf(cosv, cand_w[2], fmaf(tf, cand_w[3], cand_b[1]));
        const float e2 = fmaf(cosv, cand_w[4], fmaf(tf, cand_w[5], cand_b[2]));
        const float e3 = fmaf(cosv, cand_w[6], fmaf(tf, cand_w[7], cand_b[3]));
        tail = e0 * t4.x + e1 * t4.y + e2 * t4.z + e3 * t4.w + dense_b[candv];
    }

#pragma unroll
    for (int i = 0; i < 16; ++i) {
        float p;
        if (BF16TAB) {
            p =        bfu2f(dwb[i].x & 0xFFFFu)  * o4.x;
            p = fmaf(  bfu2f(dwb[i].x >> 16),       o4.y, p);
            p = fmaf(  bfu2f(dwb[i].y & 0xFFFFu),   o4.z, p);
            p = fmaf(  bfu2f(dwb[i].y >> 16),       o4.w, p);
        } else {
            p = dwf[i].x * o4.x + dwf[i].y * o4.y + dwf[i].z * o4.z + dwf[i].w * o4.w;
        }
        plds[wave][i][lane] = p;
    }
    __syncthreads();

    const int cc = lane >> 2;
    const int qq = lane & 3;
    float s = 0.f;
#pragma unroll
    for (int j = 0; j < 16; ++j) s += plds[wave][cc][qq * 16 + j];
    s += __shfl_xor(s, 1, 64);
    s += __shfl_xor(s, 2, 64);
    const float tl = __shfl(tail, cc, 64);
    if (qq == 0) logits[(size_t)b * NCAND + mbase + cc] = s + tl;
}

extern "C" void kernel_launch(void* const* d_in, const int* in_sizes, int n_in,
                              void* d_out, int out_size, void* d_ws, size_t ws_size,
                              hipStream_t stream) {
    const int*   src         = (const int*)d_in[0];
    const int*   dest        = (const int*)d_in[1];
    const int*   tt          = (const int*)d_in[2];
    const int*   candidates  = (const int*)d_in[3];
    const float* offset      = (const float*)d_in[4];
    const float* emb_feat    = (const float*)d_in[5];
    const float* emb_dest    = (const float*)d_in[6];
    const float* w1          = (const float*)d_in[7];
    const float* b1          = (const float*)d_in[8];
    const float* bn_gamma    = (const float*)d_in[9];
    const float* bn_beta     = (const float*)d_in[10];
    const float* bn_mean     = (const float*)d_in[11];
    const float* bn_var      = (const float*)d_in[12];
    const float* w2          = (const float*)d_in[13];
    const float* b2          = (const float*)d_in[14];
    const float* dense_w     = (const float*)d_in[15];
    const float* dense_b     = (const float*)d_in[16];
    const float* cand_w      = (const float*)d_in[17];
    const float* cand_b      = (const float*)d_in[18];
    const float* segs_src    = (const float*)d_in[19];
    const float* segs_trg    = (const float*)d_in[20];
    const float* traffic_pop = (const float*)d_in[21];

    float* out_ws = (float*)d_ws;                               // 4 MB
    const size_t OUT_WS_BYTES = (size_t)BATCH * DM8 * 4;        // 4,194,304
    const size_t WTAB_BYTES = (size_t)SEGN * DWC * 2;           // 50,400,000
    short* wtab = (short*)((char*)d_ws + OUT_WS_BYTES);
    const bool use_bf16 = ws_size >= OUT_WS_BYTES + WTAB_BYTES;
    float* logits = (float*)d_out;

    const int nblk = use_bf16 ? (BATCH / 16) * 2 : (BATCH / 16);
    mlp_conv_kernel<<<nblk, 512, 0, stream>>>(
        src, dest, offset, emb_feat, emb_dest,
        w1, b1, bn_gamma, bn_beta, bn_mean, bn_var, w2, b2,
        dense_w, wtab, out_ws);

    if (use_bf16) {
        logits_kernel_t<true><<<BATCH, 256, 0, stream>>>(
            dest, tt, candidates, dense_w, (const unsigned short*)wtab, dense_b,
            cand_w, cand_b, segs_src, segs_trg, traffic_pop, out_ws, logits);
    } else {
        logits_kernel_t<false><<<BATCH, 256, 0, stream>>>(
            dest, tt, candidates, dense_w, (const unsigned short*)wtab, dense_b,
            cand_w, cand_b, segs_src, segs_trg, traffic_pop, out_ws, logits);
    }
}

// Round 6
// 83.027 us; speedup vs baseline: 1.8893x; 1.0405x over previous
//
#include <hip/hip_runtime.h>

// KeySegPred — round 6: de-fused 3-kernel pipeline, all-bf16 weight tables.
//   K1 conv_kernel   (2048x256): dense_w -> wtab bf16 (4x-ILP stream);
//                                w1[:, :256] -> w1tab bf16; w2 -> w2tab bf16
//   K2 mlp_kernel    (256x512) : MFMA MLP, B-fragments straight from bf16 tables
//   K3 logits_kernel (4096x256): 16-deep bf16 row gather + LDS transpose-reduce
//   Fallback (ws too small): inline-convert MLP + fp32 logits gather.

#define BATCH 4096
#define DSEG 128
#define DS_ 258
#define DM7 512
#define DM8 256
#define NCAND 64
#define DWC 252
#define TSLOTS 96
#define SEGN 100000
#define CONV_BLOCKS 2048
#define CONV_DW_BLOCKS 2016

typedef short bf16x8 __attribute__((ext_vector_type(8)));
typedef short bf16x4 __attribute__((ext_vector_type(4)));
typedef float f32x4 __attribute__((ext_vector_type(4)));

static __device__ __forceinline__ short f2bf(float f) {
    union { float f; unsigned u; } v; v.f = f;
    unsigned r = (v.u + 0x7FFFu + ((v.u >> 16) & 1u)) >> 16;  // RNE
    return (short)r;
}
static __device__ __forceinline__ bf16x4 cvt4(float4 v) {
    bf16x4 s;
    s[0] = f2bf(v.x); s[1] = f2bf(v.y); s[2] = f2bf(v.z); s[3] = f2bf(v.w);
    return s;
}
static __device__ __forceinline__ float bfu2f(unsigned u16) {
    union { unsigned u; float f; } v; v.u = u16 << 16; return v.f;
}

__global__ __launch_bounds__(256) void conv_kernel(
    const float* __restrict__ dense_w, const float* __restrict__ w1,
    const float* __restrict__ w2,
    short* __restrict__ wtab, short* __restrict__ w1tab, short* __restrict__ w2tab)
{
    const int tid = threadIdx.x;
    if (blockIdx.x < CONV_DW_BLOCKS) {
        const size_t S = (size_t)CONV_DW_BLOCKS * 256;
        const size_t n4 = (size_t)SEGN * DWC / 4;   // 6,300,000 float4 groups
        size_t i = (size_t)blockIdx.x * 256 + tid;
        const float4* __restrict__ s4 = (const float4*)dense_w;
        bf16x4* __restrict__ d4 = (bf16x4*)wtab;
        for (; i + 3 * S < n4; i += 4 * S) {      // 4 loads in flight
            const float4 v0 = s4[i];
            const float4 v1 = s4[i + S];
            const float4 v2 = s4[i + 2 * S];
            const float4 v3 = s4[i + 3 * S];
            d4[i]         = cvt4(v0);
            d4[i + S]     = cvt4(v1);
            d4[i + 2 * S] = cvt4(v2);
            d4[i + 3 * S] = cvt4(v3);
        }
        for (; i < n4; i += S) d4[i] = cvt4(s4[i]);
    } else if (blockIdx.x < CONV_DW_BLOCKS + 16) {
        // w1tab[n][k<256]; skip fp32 tail cols 256,257 (kept exact elsewhere)
        for (int e = (blockIdx.x - CONV_DW_BLOCKS) * 256 + tid; e < 32768; e += 4096) {
            const int n = e >> 6, k4 = e & 63;
            const float4 v = *(const float4*)(w1 + (size_t)n * DS_ + k4 * 4);
            *(bf16x4*)(w1tab + n * 256 + k4 * 4) = cvt4(v);
        }
    } else {
        for (int e = (blockIdx.x - CONV_DW_BLOCKS - 16) * 256 + tid; e < 32768; e += 4096) {
            const float4 v = *(const float4*)(w2 + (size_t)e * 4);
            *(bf16x4*)(w2tab + (size_t)e * 4) = cvt4(v);
        }
    }
}

template <bool TAB>
__global__ __launch_bounds__(512) void mlp_kernel_t(
    const int* __restrict__ src, const int* __restrict__ dest,
    const float* __restrict__ offset,
    const float* __restrict__ emb_feat, const float* __restrict__ emb_dest,
    const float* __restrict__ w1, const float* __restrict__ b1,
    const float* __restrict__ bn_gamma, const float* __restrict__ bn_beta,
    const float* __restrict__ bn_mean, const float* __restrict__ bn_var,
    const float* __restrict__ w2, const float* __restrict__ b2,
    const short* __restrict__ w1tab, const short* __restrict__ w2tab,
    float* __restrict__ out_ws)
{
    __shared__ __align__(16) short hlds[16][520];
    const int tid = threadIdx.x;
    const int w    = tid >> 6;
    const int lane = tid & 63;
    const int lg   = lane >> 4;
    const int lr   = lane & 15;
    const int b0   = blockIdx.x * 16;

    const int si = src[b0 + lr];
    const int di = dest[b0 + lr];
    const float* fb = emb_feat + (size_t)si * DSEG;
    const float* db = emb_dest + (size_t)di * DSEG;
    bf16x8 a1[8];
#pragma unroll
    for (int s = 0; s < 8; ++s) {
        const float* p = (s < 4) ? (fb + s * 32 + lg * 8)
                                 : (db + (s - 4) * 32 + lg * 8);
        const float4 x = *(const float4*)p;
        const float4 y = *(const float4*)(p + 4);
        bf16x8 t;
        t[0] = f2bf(x.x); t[1] = f2bf(x.y); t[2] = f2bf(x.z); t[3] = f2bf(x.w);
        t[4] = f2bf(y.x); t[5] = f2bf(y.y); t[6] = f2bf(y.z); t[7] = f2bf(y.w);
        a1[s] = t;
    }
    float off1[4], off2[4];
#pragma unroll
    for (int q = 0; q < 4; ++q) {
        const float4 o = *(const float4*)(offset + (size_t)(b0 + lg * 4 + q) * 4);
        off1[q] = o.y; off2[q] = o.z;
    }

#pragma unroll
    for (int nt = 0; nt < 4; ++nt) {
        const int n = (w * 4 + nt) * 16 + lr;
        f32x4 acc = {0.f, 0.f, 0.f, 0.f};
#pragma unroll
        for (int s = 0; s < 8; ++s) {
            bf16x8 bb;
            if (TAB) {
                bb = *(const bf16x8*)(w1tab + (size_t)n * 256 + s * 32 + lg * 8);
            } else {
                const float* p = w1 + (size_t)n * DS_ + s * 32 + lg * 8;
                const float2 x0 = *(const float2*)(p);
                const float2 x1 = *(const float2*)(p + 2);
                const float2 x2 = *(const float2*)(p + 4);
                const float2 x3 = *(const float2*)(p + 6);
                bb[0] = f2bf(x0.x); bb[1] = f2bf(x0.y); bb[2] = f2bf(x1.x); bb[3] = f2bf(x1.y);
                bb[4] = f2bf(x2.x); bb[5] = f2bf(x2.y); bb[6] = f2bf(x3.x); bb[7] = f2bf(x3.y);
            }
            acc = __builtin_amdgcn_mfma_f32_16x16x32_bf16(a1[s], bb, acc, 0, 0, 0);
        }
        const float2 wtail = *(const float2*)(w1 + (size_t)n * DS_ + 256);
        const float scale = bn_gamma[n] / sqrtf(bn_var[n] + 1e-6f);
        const float shift = bn_beta[n] - bn_mean[n] * scale;
        const float bias  = b1[n];
#pragma unroll
        for (int q = 0; q < 4; ++q) {
            float v = acc[q] + bias + off1[q] * wtail.x + off2[q] * wtail.y;
            v = fmaf(v, scale, shift);
            v = fmaxf(v, 0.f);
            hlds[lg * 4 + q][n] = f2bf(v);
        }
    }
    __syncthreads();

    bf16x8 a2[16];
#pragma unroll
    for (int s = 0; s < 16; ++s) {
        a2[s] = *(const bf16x8*)&hlds[lr][s * 32 + lg * 8];
    }
#pragma unroll
    for (int nt = 0; nt < 2; ++nt) {
        const int n = (w * 2 + nt) * 16 + lr;
        f32x4 acc = {0.f, 0.f, 0.f, 0.f};
#pragma unroll
        for (int s = 0; s < 16; ++s) {
            bf16x8 bb;
            if (TAB) {
                bb = *(const bf16x8*)(w2tab + (size_t)n * 512 + s * 32 + lg * 8);
            } else {
                const float4 x = *(const float4*)(w2 + (size_t)n * DM7 + s * 32 + lg * 8);
                const float4 y = *(const float4*)(w2 + (size_t)n * DM7 + s * 32 + lg * 8 + 4);
                bb[0] = f2bf(x.x); bb[1] = f2bf(x.y); bb[2] = f2bf(x.z); bb[3] = f2bf(x.w);
                bb[4] = f2bf(y.x); bb[5] = f2bf(y.y); bb[6] = f2bf(y.z); bb[7] = f2bf(y.w);
            }
            acc = __builtin_amdgcn_mfma_f32_16x16x32_bf16(a2[s], bb, acc, 0, 0, 0);
        }
        const float bias = b2[n];
#pragma unroll
        for (int q = 0; q < 4; ++q) {
            out_ws[(size_t)(b0 + lg * 4 + q) * DM8 + n] = acc[q] + bias;
        }
    }
}

template <bool BF16TAB>
__global__ __launch_bounds__(256) void logits_kernel_t(
    const int* __restrict__ dest, const int* __restrict__ tt,
    const int* __restrict__ candidates,
    const float* __restrict__ dense_w, const unsigned short* __restrict__ wtab,
    const float* __restrict__ dense_b,
    const float* __restrict__ cand_w, const float* __restrict__ cand_b,
    const float* __restrict__ segs_src, const float* __restrict__ segs_trg,
    const float* __restrict__ traffic_pop,
    const float* __restrict__ out_ws,
    float* __restrict__ logits)
{
    __shared__ float plds[4][16][67];
    const int b = blockIdx.x;
    const int tid = threadIdx.x;
    const int wave = tid >> 6;
    const int lane = tid & 63;
    const int mbase = wave * 16;

    int candv = 0;
    if (lane < 16) candv = candidates[b * NCAND + mbase + lane];

    const int ll = (lane < 63) ? lane : 62;
    float4 dwf[16];
    uint2  dwb[16];
    if (BF16TAB) {
#pragma unroll
        for (int i = 0; i < 16; ++i) {
            const int ci = __shfl(candv, i, 64);
            dwb[i] = *(const uint2*)(wtab + (size_t)ci * DWC + ll * 4);  // 8B/lane
        }
    } else {
#pragma unroll
        for (int i = 0; i < 16; ++i) {
            const int ci = __shfl(candv, i, 64);
            dwf[i] = *(const float4*)(dense_w + (size_t)ci * DWC + ll * 4);
        }
    }

    float4 o4 = *(const float4*)(out_ws + (size_t)b * DM8 + ll * 4);
    if (lane == 63) { o4.x = 0.f; o4.y = 0.f; o4.z = 0.f; o4.w = 0.f; }

    float tail = 0.f;
    if (lane < 16) {
        const float4 t4 = *(const float4*)(out_ws + (size_t)b * DM8 + DWC);
        const int db = dest[b];
        const float2 dsx = *(const float2*)(segs_src + 2 * (size_t)db);
        const float2 sx = *(const float2*)(segs_src + 2 * (size_t)candv);
        const float2 tx = *(const float2*)(segs_trg + 2 * (size_t)candv);
        const float v1x = dsx.x - sx.x, v1y = dsx.y - sx.y;
        const float v2x = tx.x - sx.x, v2y = tx.y - sx.y;
        const float num = v1x * v2x + v1y * v2y;
        const float den = fmaxf(sqrtf(v1x * v1x + v1y * v1y) *
                                sqrtf(v2x * v2x + v2y * v2y), 1e-8f);
        const float cosv = num / den;
        const float tf = traffic_pop[(size_t)candv * TSLOTS + tt[b]];
        const float e0 = fmaf(cosv, cand_w[0], fmaf(tf, cand_w[1], cand_b[0]));
        const float e1 = fmaf(cosv, cand_w[2], fmaf(tf, cand_w[3], cand_b[1]));
        const float e2 = fmaf(cosv, cand_w[4], fmaf(tf, cand_w[5], cand_b[2]));
        const float e3 = fmaf(cosv, cand_w[6], fmaf(tf, cand_w[7], cand_b[3]));
        tail = e0 * t4.x + e1 * t4.y + e2 * t4.z + e3 * t4.w + dense_b[candv];
    }

#pragma unroll
    for (int i = 0; i < 16; ++i) {
        float p;
        if (BF16TAB) {
            p =      bfu2f(dwb[i].x & 0xFFFFu) * o4.x;
            p = fmaf(bfu2f(dwb[i].x >> 16),      o4.y, p);
            p = fmaf(bfu2f(dwb[i].y & 0xFFFFu),  o4.z, p);
            p = fmaf(bfu2f(dwb[i].y >> 16),      o4.w, p);
        } else {
            p = dwf[i].x * o4.x + dwf[i].y * o4.y + dwf[i].z * o4.z + dwf[i].w * o4.w;
        }
        plds[wave][i][lane] = p;
    }
    __syncthreads();

    const int cc = lane >> 2;
    const int qq = lane & 3;
    float s = 0.f;
#pragma unroll
    for (int j = 0; j < 16; ++j) s += plds[wave][cc][qq * 16 + j];
    s += __shfl_xor(s, 1, 64);
    s += __shfl_xor(s, 2, 64);
    const float tl = __shfl(tail, cc, 64);
    if (qq == 0) logits[(size_t)b * NCAND + mbase + cc] = s + tl;
}

extern "C" void kernel_launch(void* const* d_in, const int* in_sizes, int n_in,
                              void* d_out, int out_size, void* d_ws, size_t ws_size,
                              hipStream_t stream) {
    const int*   src         = (const int*)d_in[0];
    const int*   dest        = (const int*)d_in[1];
    const int*   tt          = (const int*)d_in[2];
    const int*   candidates  = (const int*)d_in[3];
    const float* offset      = (const float*)d_in[4];
    const float* emb_feat    = (const float*)d_in[5];
    const float* emb_dest    = (const float*)d_in[6];
    const float* w1          = (const float*)d_in[7];
    const float* b1          = (const float*)d_in[8];
    const float* bn_gamma    = (const float*)d_in[9];
    const float* bn_beta     = (const float*)d_in[10];
    const float* bn_mean     = (const float*)d_in[11];
    const float* bn_var      = (const float*)d_in[12];
    const float* w2          = (const float*)d_in[13];
    const float* b2          = (const float*)d_in[14];
    const float* dense_w     = (const float*)d_in[15];
    const float* dense_b     = (const float*)d_in[16];
    const float* cand_w      = (const float*)d_in[17];
    const float* cand_b      = (const float*)d_in[18];
    const float* segs_src    = (const float*)d_in[19];
    const float* segs_trg    = (const float*)d_in[20];
    const float* traffic_pop = (const float*)d_in[21];

    float* out_ws = (float*)d_ws;
    const size_t OUT_WS_BYTES = (size_t)BATCH * DM8 * 4;        //  4,194,304
    const size_t WTAB_BYTES   = (size_t)SEGN * DWC * 2;         // 50,400,000
    const size_t W1TAB_BYTES  = (size_t)DM7 * 256 * 2;          //    262,144
    const size_t W2TAB_BYTES  = (size_t)DM8 * DM7 * 2;          //    262,144
    short* wtab  = (short*)((char*)d_ws + OUT_WS_BYTES);
    short* w1tab = (short*)((char*)d_ws + OUT_WS_BYTES + WTAB_BYTES);
    short* w2tab = (short*)((char*)d_ws + OUT_WS_BYTES + WTAB_BYTES + W1TAB_BYTES);
    const bool use_tab =
        ws_size >= OUT_WS_BYTES + WTAB_BYTES + W1TAB_BYTES + W2TAB_BYTES;
    float* logits = (float*)d_out;

    if (use_tab) {
        conv_kernel<<<CONV_BLOCKS, 256, 0, stream>>>(dense_w, w1, w2, wtab, w1tab, w2tab);
        mlp_kernel_t<true><<<BATCH / 16, 512, 0, stream>>>(
            src, dest, offset, emb_feat, emb_dest,
            w1, b1, bn_gamma, bn_beta, bn_mean, bn_var, w2, b2, w1tab, w2tab, out_ws);
        logits_kernel_t<true><<<BATCH, 256, 0, stream>>>(
            dest, tt, candidates, dense_w, (const unsigned short*)wtab, dense_b,
            cand_w, cand_b, segs_src, segs_trg, traffic_pop, out_ws, logits);
    } else {
        mlp_kernel_t<false><<<BATCH / 16, 512, 0, stream>>>(
            src, dest, offset, emb_feat, emb_dest,
            w1, b1, bn_gamma, bn_beta, bn_mean, bn_var, w2, b2, w1tab, w2tab, out_ws);
        logits_kernel_t<false><<<BATCH, 256, 0, stream>>>(
            dest, tt, candidates, dense_w, (const unsigned short*)wtab, dense_b,
            cand_w, cand_b, segs_src, segs_trg, traffic_pop, out_ws, logits);
    }
}